// Round 1
// baseline (1497.963 us; speedup 1.0000x reference)
//
#include <hip/hip_runtime.h>
#include <stdint.h>

#define B_DIM 32768
#define I_DIM 384
#define U_DIM 128
#define E_DIM 8
#define G_DIM 256
#define ALPHA 0.1f
#define BETA 0.1f

typedef __attribute__((ext_vector_type(8))) short s16x8;
typedef __attribute__((ext_vector_type(4))) float f32x4;
typedef __attribute__((ext_vector_type(4))) unsigned short u16x4;
typedef __attribute__((ext_vector_type(4))) unsigned int u32x4;

static __device__ __forceinline__ unsigned short f2bf(float f) {
  unsigned u = __builtin_bit_cast(unsigned, f);
  u = u + 0x7FFFu + ((u >> 16) & 1u);   // round-to-nearest-even bf16
  return (unsigned short)(u >> 16);
}

// ---------------------------------------------------------------------------
// Kernel 1: convert the 3 expert weight banks [8,128,384] f32 -> bf16 in ws.
// ---------------------------------------------------------------------------
__global__ __launch_bounds__(256) void k_wconv(const float* __restrict__ w0,
                                               const float* __restrict__ w1,
                                               const float* __restrict__ w2,
                                               unsigned short* __restrict__ dst) {
  const int q = blockIdx.x * 256 + threadIdx.x;      // quad index, 294912 total
  const int per = E_DIM * U_DIM * I_DIM / 4;         // 98304 quads per bank
  const float* src = (q < per) ? w0 : (q < 2 * per) ? w1 : w2;
  const int lq = q % per;
  const f32x4 v = *(const f32x4*)(src + (size_t)lq * 4);
  u16x4 p;
  p.x = f2bf(v.x); p.y = f2bf(v.y); p.z = f2bf(v.z); p.w = f2bf(v.w);
  *(u16x4*)(dst + (size_t)q * 4) = p;
}

// ---------------------------------------------------------------------------
// Kernel 2: all 9 gates (softmax) folded into 8 coefficient vectors A[b][64].
// One wave per row. LDS per wave: x_t1|x_t2|x_sh (384 each), ui|up|ip (256
// each) then 104 logits at offset 1920.
// A vector order: 0:A1_sh 1:A1_t1 2:A1_t2 3:A2_sh 4:A2_t2 5:Ash_t1 6:Ash_sh 7:Ash_t2
// ---------------------------------------------------------------------------
__global__ __launch_bounds__(256) void k_gates(
    const float* __restrict__ xsh, const float* __restrict__ xt1, const float* __restrict__ xt2,
    const float* __restrict__ ui, const float* __restrict__ up, const float* __restrict__ ip,
    const float* __restrict__ Wg_sh, const float* __restrict__ bg_sh,
    const float* __restrict__ Wg_t1, const float* __restrict__ bg_t1,
    const float* __restrict__ Wg_t2, const float* __restrict__ bg_t2,
    const float* __restrict__ Wg_sh2, const float* __restrict__ bg_sh2,
    const float* __restrict__ Wg_t2ip, const float* __restrict__ bg_t2ip,
    const float* __restrict__ Wg_t2up, const float* __restrict__ bg_t2up,
    const float* __restrict__ Wg_s1ip, const float* __restrict__ bg_s1ip,
    const float* __restrict__ Wg_s1up, const float* __restrict__ bg_s1up,
    const float* __restrict__ Wg_t1ui, const float* __restrict__ bg_t1ui,
    float* __restrict__ A) {
  __shared__ float lds[4][2048];
  const int wid = threadIdx.x >> 6, lane = threadIdx.x & 63;
  float* wb = lds[wid];

  for (int it = 0; it < 8; ++it) {
    const int r = blockIdx.x * 32 + it * 4 + wid;
    // ---- stage row data ----
    for (int i = lane; i < 384; i += 64) {
      wb[i]       = xt1[(size_t)r * 384 + i];
      wb[384 + i] = xt2[(size_t)r * 384 + i];
      wb[768 + i] = xsh[(size_t)r * 384 + i];
    }
    for (int i = lane; i < 256; i += 64) {
      wb[1152 + i] = ui[(size_t)r * 256 + i];
      wb[1408 + i] = up[(size_t)r * 256 + i];
      wb[1664 + i] = ip[(size_t)r * 256 + i];
    }
    __syncthreads();
    // ---- x-gate logits: lanes 0..55 ----
    if (lane < 56) {
      const float* wrow; const float* xb; float acc;
      if (lane < 16)      { wrow = Wg_t1 + lane * 384;        xb = wb;       acc = bg_t1[lane]; }
      else if (lane < 32) { wrow = Wg_t2 + (lane - 16) * 384; xb = wb + 384; acc = bg_t2[lane - 16]; }
      else                { wrow = Wg_sh + (lane - 32) * 384; xb = wb + 768; acc = bg_sh[lane - 32]; }
      for (int k = 0; k < 384; k += 4) {
        const f32x4 w = *(const f32x4*)(wrow + k);
        acc += w.x * xb[k] + w.y * xb[k + 1] + w.z * xb[k + 2] + w.w * xb[k + 3];
      }
      wb[1920 + lane] = acc;
    }
    // ---- key-gate logits: lanes 0..47 (order: s1ip s1up t1ui sh2 t2up t2ip)
    if (lane < 48) {
      const int g = lane >> 3, j = lane & 7;
      const float* wrow; float acc; const float* xb;
      if (g == 0)      { wrow = Wg_s1ip + j * 256; acc = bg_s1ip[j]; xb = wb + 1664; }
      else if (g == 1) { wrow = Wg_s1up + j * 256; acc = bg_s1up[j]; xb = wb + 1408; }
      else if (g == 2) { wrow = Wg_t1ui + j * 256; acc = bg_t1ui[j]; xb = wb + 1152; }
      else if (g == 3) { wrow = Wg_sh2  + j * 256; acc = bg_sh2[j];  xb = wb + 1152; }
      else if (g == 4) { wrow = Wg_t2up + j * 256; acc = bg_t2up[j]; xb = wb + 1408; }
      else             { wrow = Wg_t2ip + j * 256; acc = bg_t2ip[j]; xb = wb + 1664; }
      for (int k = 0; k < 256; k += 4) {
        const f32x4 w = *(const f32x4*)(wrow + k);
        acc += w.x * xb[k] + w.y * xb[k + 1] + w.z * xb[k + 2] + w.w * xb[k + 3];
      }
      wb[1976 + lane] = acc;
    }
    __syncthreads();
    // ---- 9 softmaxes, one per lane ----
    if (lane < 9) {
      int off, n;
      if (lane == 0)      { off = 1920; n = 16; }
      else if (lane == 1) { off = 1936; n = 16; }
      else if (lane == 2) { off = 1952; n = 24; }
      else                { off = 1976 + (lane - 3) * 8; n = 8; }
      float* p = wb + off;
      float m = p[0];
      for (int i = 1; i < n; ++i) m = fmaxf(m, p[i]);
      float ssum = 0.f;
      for (int i = 0; i < n; ++i) { const float ev = expf(p[i] - m); p[i] = ev; ssum += ev; }
      const float inv = 1.f / ssum;
      for (int i = 0; i < n; ++i) p[i] *= inv;
    }
    __syncthreads();
    // ---- combine into A (lane = v*8 + e) ----
    {
      const int ee = lane & 7, v = lane >> 3;
      float val = 0.f;
      switch (v) {
        case 0: val = wb[1920 + ee] + ALPHA * wb[1976 + ee]; break;              // A1_sh
        case 1: val = wb[1928 + ee]; break;                                      // A1_t1
        case 2: val = ALPHA * (wb[1984 + ee] + wb[1992 + ee]); break;            // A1_t2
        case 3: val = wb[1936 + ee] + BETA * wb[2000 + ee]; break;               // A2_sh
        case 4: val = wb[1944 + ee] + BETA * (wb[2008 + ee] + wb[2016 + ee]); break; // A2_t2
        case 5: val = wb[1952 + ee]; break;                                      // Ash_t1
        case 6: val = wb[1960 + ee]; break;                                      // Ash_sh
        case 7: val = wb[1968 + ee]; break;                                      // Ash_t2
      }
      A[(size_t)r * 64 + lane] = val;
    }
    __syncthreads();
  }
}

// ---------------------------------------------------------------------------
// Kernel 3: fused expert GEMM (bf16 MFMA) + bias + relu + permuted mix.
// Block = (e = bid&7, mt = bid>>3). Source rows [mt*128, mt*128+128),
// output rows b' = e*4096 + mt*16 + o, o in [0,16).
// 128x128 tile, BK=64, 4 waves (2x2 quadrants), mfma_f32_16x16x32_bf16.
// ---------------------------------------------------------------------------
__global__ __launch_bounds__(256) void k_moe(
    const float* __restrict__ xsh, const float* __restrict__ xt1, const float* __restrict__ xt2,
    const unsigned short* __restrict__ Wbf,
    const float* __restrict__ bsh, const float* __restrict__ bt1, const float* __restrict__ bt2,
    const float* __restrict__ A, float* __restrict__ out) {
  __shared__ union {
    struct { unsigned short xs[128 * 64]; unsigned short wsb[128 * 64]; } st;
    float S[128 * 128];
  } sm;

  const int tid = threadIdx.x;
  const int lane = tid & 63, wid = tid >> 6;
  const int wr = wid >> 1, wc = wid & 1;
  const int lo = lane & 15, hi = lane >> 4;
  const int e = blockIdx.x & 7, mt = blockIdx.x >> 3;
  const int R0 = mt * 128;
  const int b0 = e * 4096 + mt * 16;
  const int o = tid >> 4, u0 = (tid & 15) * 8;

  float oacc[3][8] = {};   // [out_sh, out1, out2][u]

  const float* xp[3] = { xsh, xt1, xt2 };
  const float* bp[3] = { bsh, bt1, bt2 };
  const int a0i[3] = { 6, 5, 7 };   // coef vec for out_sh per set
  const int a1i[3] = { 0, 1, 2 };   // coef vec for out1 per set
  const int a2i[3] = { 3, 0, 4 };   // coef vec for out2 per set (s==1 masked)

#pragma unroll
  for (int s = 0; s < 3; ++s) {
    const float* __restrict__ X = xp[s];
    const unsigned short* __restrict__ W = Wbf + (size_t)(s * 8 + e) * (128 * 384);
    f32x4 acc[4][4];
#pragma unroll
    for (int i = 0; i < 4; ++i)
#pragma unroll
      for (int j = 0; j < 4; ++j) acc[i][j] = 0.f;

    for (int kc = 0; kc < 6; ++kc) {
      // stage X tile [128 x 64] f32 -> bf16 LDS
#pragma unroll
      for (int j = 0; j < 8; ++j) {
        const int un = tid + j * 256;                 // 0..2047
        const int row = un >> 4, c4 = (un & 15) << 2;
        const f32x4 v = *(const f32x4*)(X + (size_t)(R0 + row) * 384 + kc * 64 + c4);
        u16x4 p;
        p.x = f2bf(v.x); p.y = f2bf(v.y); p.z = f2bf(v.z); p.w = f2bf(v.w);
        *(u16x4*)(&sm.st.xs[un << 2]) = p;
      }
      // stage W tile [128 x 64] bf16 LDS
#pragma unroll
      for (int j = 0; j < 4; ++j) {
        const int un = tid + j * 256;                 // 0..1023
        const u32x4 v = *(const u32x4*)(W + (un >> 3) * 384 + kc * 64 + ((un & 7) << 3));
        *(u32x4*)(&sm.st.wsb[un << 3]) = v;
      }
      __syncthreads();
#pragma unroll
      for (int kk = 0; kk < 2; ++kk) {
        s16x8 av[4], bv[4];
#pragma unroll
        for (int f = 0; f < 4; ++f) {
          av[f] = *(const s16x8*)(&sm.st.xs[(wr * 64 + f * 16 + lo) * 64 + kk * 32 + hi * 8]);
          bv[f] = *(const s16x8*)(&sm.st.wsb[(wc * 64 + f * 16 + lo) * 64 + kk * 32 + hi * 8]);
        }
#pragma unroll
        for (int fm = 0; fm < 4; ++fm)
#pragma unroll
          for (int fn = 0; fn < 4; ++fn)
            acc[fm][fn] = __builtin_amdgcn_mfma_f32_16x16x32_bf16(av[fm], bv[fn], acc[fm][fn], 0, 0, 0);
      }
      __syncthreads();
    }
    // ---- epilogue: S = relu(acc + bias) into LDS (f32) ----
#pragma unroll
    for (int fn = 0; fn < 4; ++fn) {
      const int c = wc * 64 + fn * 16 + lo;
      const float bias = bp[s][e * 128 + c];
#pragma unroll
      for (int fm = 0; fm < 4; ++fm) {
        const int rb = wr * 64 + fm * 16 + hi * 4;
#pragma unroll
        for (int j = 0; j < 4; ++j)
          sm.S[(rb + j) * 128 + c] = fmaxf(acc[fm][fn][j] + bias, 0.f);
      }
    }
    __syncthreads();
    // ---- permuted mix: out_k[b0+o] += sum_e' A[..] * S[o*8+e', :] ----
    {
      const float* __restrict__ Arow = A + (size_t)(b0 + o) * 64;
#pragma unroll
      for (int ep = 0; ep < 8; ++ep) {
        const float* Srow = &sm.S[(o * 8 + ep) * 128 + u0];
        const float c0 = Arow[a0i[s] * 8 + ep];
        const float c1 = Arow[a1i[s] * 8 + ep];
        const float c2 = (s == 1) ? 0.f : Arow[a2i[s] * 8 + ep];
#pragma unroll
        for (int u = 0; u < 8; ++u) {
          const float sv = Srow[u];
          oacc[0][u] = fmaf(c0, sv, oacc[0][u]);
          oacc[1][u] = fmaf(c1, sv, oacc[1][u]);
          oacc[2][u] = fmaf(c2, sv, oacc[2][u]);
        }
      }
    }
    __syncthreads();
  }
  // ---- write the three outputs ----
#pragma unroll
  for (int k = 0; k < 3; ++k) {
    float* dst = out + (size_t)k * (B_DIM * 128) + (size_t)(b0 + o) * 128 + u0;
    f32x4 v0, v1;
#pragma unroll
    for (int u = 0; u < 4; ++u) { v0[u] = oacc[k][u]; v1[u] = oacc[k][4 + u]; }
    *(f32x4*)(dst) = v0;
    *(f32x4*)(dst + 4) = v1;
  }
}

// ---------------------------------------------------------------------------
extern "C" void kernel_launch(void* const* d_in, const int* in_sizes, int n_in,
                              void* d_out, int out_size, void* d_ws, size_t ws_size,
                              hipStream_t stream) {
  const float* xsh = (const float*)d_in[0];
  const float* xt1 = (const float*)d_in[1];
  const float* xt2 = (const float*)d_in[2];
  const float* ui  = (const float*)d_in[3];
  const float* up  = (const float*)d_in[4];
  const float* ip  = (const float*)d_in[5];
  const float* Wsh = (const float*)d_in[6];   const float* bsh = (const float*)d_in[7];
  const float* Wt1 = (const float*)d_in[8];   const float* bt1 = (const float*)d_in[9];
  const float* Wt2 = (const float*)d_in[10];  const float* bt2 = (const float*)d_in[11];
  const float* Wg_sh  = (const float*)d_in[12];  const float* bg_sh  = (const float*)d_in[13];
  const float* Wg_t1  = (const float*)d_in[14];  const float* bg_t1  = (const float*)d_in[15];
  const float* Wg_t2  = (const float*)d_in[16];  const float* bg_t2  = (const float*)d_in[17];
  const float* Wg_sh2 = (const float*)d_in[18];  const float* bg_sh2 = (const float*)d_in[19];
  const float* Wg_t2ip = (const float*)d_in[20]; const float* bg_t2ip = (const float*)d_in[21];
  const float* Wg_t2up = (const float*)d_in[22]; const float* bg_t2up = (const float*)d_in[23];
  const float* Wg_s1ip = (const float*)d_in[24]; const float* bg_s1ip = (const float*)d_in[25];
  const float* Wg_s1up = (const float*)d_in[26]; const float* bg_s1up = (const float*)d_in[27];
  const float* Wg_t1ui = (const float*)d_in[28]; const float* bg_t1ui = (const float*)d_in[29];

  unsigned short* Wbf = (unsigned short*)d_ws;              // 3*8*128*384*2 = 2,359,296 B
  float* A = (float*)((char*)d_ws + 2359296);               // 32768*64*4    = 8,388,608 B
  float* out = (float*)d_out;

  hipLaunchKernelGGL(k_wconv, dim3(1152), dim3(256), 0, stream, Wsh, Wt1, Wt2, Wbf);
  hipLaunchKernelGGL(k_gates, dim3(1024), dim3(256), 0, stream,
                     xsh, xt1, xt2, ui, up, ip,
                     Wg_sh, bg_sh, Wg_t1, bg_t1, Wg_t2, bg_t2, Wg_sh2, bg_sh2,
                     Wg_t2ip, bg_t2ip, Wg_t2up, bg_t2up, Wg_s1ip, bg_s1ip,
                     Wg_s1up, bg_s1up, Wg_t1ui, bg_t1ui, A);
  hipLaunchKernelGGL(k_moe, dim3(2048), dim3(256), 0, stream,
                     xsh, xt1, xt2, Wbf, bsh, bt1, bt2, A, out);
}

// Round 5
// 585.735 us; speedup vs baseline: 2.5574x; 2.5574x over previous
//
#include <hip/hip_runtime.h>
#include <stdint.h>

#define B_DIM 32768
#define I_DIM 384
#define U_DIM 128
#define E_DIM 8
#define G_DIM 256
#define ALPHA 0.1f
#define BETA 0.1f

typedef __attribute__((ext_vector_type(8))) short s16x8;
typedef __attribute__((ext_vector_type(4))) float f32x4;
typedef __attribute__((ext_vector_type(4))) unsigned short u16x4;
typedef __attribute__((ext_vector_type(4))) unsigned int u32x4;

static __device__ __forceinline__ unsigned short f2bf(float f) {
  unsigned u = __builtin_bit_cast(unsigned, f);
  u = u + 0x7FFFu + ((u >> 16) & 1u);   // round-to-nearest-even bf16
  return (unsigned short)(u >> 16);
}

// XOR swizzle: spreads the 16B column slots of an LDS row across banks (T2).
#define SWZB(row, b) ((b) ^ (((row) & 7) << 4))

// ---------------------------------------------------------------------------
// Kernel 1: convert the 3 expert weight banks [8,128,384] f32 -> bf16 in ws.
// ---------------------------------------------------------------------------
__global__ __launch_bounds__(256) void k_wconv(const float* __restrict__ w0,
                                               const float* __restrict__ w1,
                                               const float* __restrict__ w2,
                                               unsigned short* __restrict__ dst) {
  const int q = blockIdx.x * 256 + threadIdx.x;      // quad index, 294912 total
  const int per = E_DIM * U_DIM * I_DIM / 4;         // 98304 quads per bank
  const float* src = (q < per) ? w0 : (q < 2 * per) ? w1 : w2;
  const int lq = q % per;
  const f32x4 v = *(const f32x4*)(src + (size_t)lq * 4);
  u16x4 p;
  p.x = f2bf(v.x); p.y = f2bf(v.y); p.z = f2bf(v.z); p.w = f2bf(v.w);
  *(u16x4*)(dst + (size_t)q * 4) = p;
}

// ---------------------------------------------------------------------------
// Gate-logit GEMM segment: stage W block [NTILE*16][KSEG] f32->bf16 (swizzled,
// rows >= na from Wb or zero), then K-loop over KSEG staging X [64][64] and
// issuing NTILE MFMAs per kk. acc[t] accumulates logit tile t.
// ---------------------------------------------------------------------------
template<int KSEG, int NTILE>
__device__ __forceinline__ void seg_gemm(
    const float* __restrict__ X,
    const float* __restrict__ Wa, int na,
    const float* __restrict__ Wb,
    int R0, int tid, unsigned short* __restrict__ xg, unsigned short* __restrict__ wg,
    f32x4* __restrict__ acc) {
  const int lane = tid & 63, wv = tid >> 6;
  const int lo = lane & 15, hi = lane >> 4;
  constexpr int CQ = KSEG / 4;               // 8B (4-elem) chunks per W row
  constexpr int CH = NTILE * 16 * CQ;
  for (int c = tid; c < CH; c += 256) {
    const int row = c / CQ, cq = c % CQ;
    u16x4 pk = {0, 0, 0, 0};
    const float* src = nullptr;
    if (row < na)            src = Wa + (size_t)row * KSEG + cq * 4;
    else if (Wb != nullptr && row < 16 + na) src = Wb + (size_t)(row - na) * KSEG + cq * 4;
    if (src != nullptr) {
      const f32x4 v = *(const f32x4*)src;
      pk.x = f2bf(v.x); pk.y = f2bf(v.y); pk.z = f2bf(v.z); pk.w = f2bf(v.w);
    }
    *(u16x4*)((char*)wg + row * (KSEG * 2) + SWZB(row, cq * 8)) = pk;
  }
  for (int kc = 0; kc < KSEG / 64; ++kc) {
    // stage X chunk [64 rows][64 cols] f32 -> bf16, swizzled
#pragma unroll
    for (int j = 0; j < 4; ++j) {
      const int un = tid + j * 256;            // 0..1023 quads
      const int row = un >> 4, c4 = (un & 15) << 2;
      const f32x4 v = *(const f32x4*)(X + (size_t)(R0 + row) * KSEG + kc * 64 + c4);
      u16x4 pk;
      pk.x = f2bf(v.x); pk.y = f2bf(v.y); pk.z = f2bf(v.z); pk.w = f2bf(v.w);
      *(u16x4*)((char*)xg + row * 128 + SWZB(row, (un & 15) << 3)) = pk;
    }
    __syncthreads();
#pragma unroll
    for (int kk = 0; kk < 2; ++kk) {
      const int ar = wv * 16 + lo;
      const s16x8 a = *(const s16x8*)((const char*)xg + ar * 128 + SWZB(ar, kk * 64 + hi * 16));
#pragma unroll
      for (int t = 0; t < NTILE; ++t) {
        const int br = t * 16 + lo;
        const s16x8 b = *(const s16x8*)((const char*)wg + br * (KSEG * 2)
                                        + SWZB(br, kc * 128 + kk * 64 + hi * 16));
        acc[t] = __builtin_amdgcn_mfma_f32_16x16x32_bf16(a, b, acc[t], 0, 0, 0);
      }
    }
    __syncthreads();
  }
}

// ---------------------------------------------------------------------------
// Kernel 2: gate logits (6 block-diagonal segments) + softmax + A-combine.
// Logit cols: 0-15 t1 | 16-31 t2 | 32-55 sh | 56-63 unused | 64-71 t1ui |
//             72-79 sh2 | 80-87 s1up | 88-95 t2up | 96-103 s1ip | 104-111 t2ip
// A[b][64] vec order: 0:A1_sh 1:A1_t1 2:A1_t2 3:A2_sh 4:A2_t2 5:Ash_t1
//                     6:Ash_sh 7:Ash_t2
// ---------------------------------------------------------------------------
__global__ __launch_bounds__(256) void k_glog(
    const float* __restrict__ xsh, const float* __restrict__ xt1, const float* __restrict__ xt2,
    const float* __restrict__ ui, const float* __restrict__ up, const float* __restrict__ ip,
    const float* __restrict__ Wg_sh, const float* __restrict__ bg_sh,
    const float* __restrict__ Wg_t1, const float* __restrict__ bg_t1,
    const float* __restrict__ Wg_t2, const float* __restrict__ bg_t2,
    const float* __restrict__ Wg_sh2, const float* __restrict__ bg_sh2,
    const float* __restrict__ Wg_t2ip, const float* __restrict__ bg_t2ip,
    const float* __restrict__ Wg_t2up, const float* __restrict__ bg_t2up,
    const float* __restrict__ Wg_s1ip, const float* __restrict__ bg_s1ip,
    const float* __restrict__ Wg_s1up, const float* __restrict__ bg_s1up,
    const float* __restrict__ Wg_t1ui, const float* __restrict__ bg_t1ui,
    float* __restrict__ A) {
  __shared__ union {
    struct { unsigned short xg[64 * 64]; unsigned short wg[32 * 384]; } st;
    float L[64 * 112];
  } sm;
  __shared__ float sbias[112];
  const int tid = threadIdx.x;
  const int lane = tid & 63, wv = tid >> 6;
  const int lo = lane & 15, hi = lane >> 4;
  const int R0 = blockIdx.x * 64;

  if (tid < 112) {
    const int r = tid; float b;
    if (r < 16)       b = bg_t1[r];
    else if (r < 32)  b = bg_t2[r - 16];
    else if (r < 56)  b = bg_sh[r - 32];
    else if (r < 64)  b = 0.f;
    else if (r < 72)  b = bg_t1ui[r - 64];
    else if (r < 80)  b = bg_sh2[r - 72];
    else if (r < 88)  b = bg_s1up[r - 80];
    else if (r < 96)  b = bg_t2up[r - 88];
    else if (r < 104) b = bg_s1ip[r - 96];
    else              b = bg_t2ip[r - 104];
    sbias[r] = b;
  }

  f32x4 acc[7];
#pragma unroll
  for (int fn = 0; fn < 7; ++fn) acc[fn] = 0.f;

  seg_gemm<384, 1>(xt1, Wg_t1, 16, nullptr, R0, tid, sm.st.xg, sm.st.wg, acc + 0);
  seg_gemm<384, 1>(xt2, Wg_t2, 16, nullptr, R0, tid, sm.st.xg, sm.st.wg, acc + 1);
  seg_gemm<384, 2>(xsh, Wg_sh, 24, nullptr, R0, tid, sm.st.xg, sm.st.wg, acc + 2);
  seg_gemm<256, 1>(ui, Wg_t1ui, 8, Wg_sh2,  R0, tid, sm.st.xg, sm.st.wg, acc + 4);
  seg_gemm<256, 1>(up, Wg_s1up, 8, Wg_t2up, R0, tid, sm.st.xg, sm.st.wg, acc + 5);
  seg_gemm<256, 1>(ip, Wg_s1ip, 8, Wg_t2ip, R0, tid, sm.st.xg, sm.st.wg, acc + 6);

  // logits (+bias) -> LDS
#pragma unroll
  for (int fn = 0; fn < 7; ++fn) {
    const int c = fn * 16 + lo;
    const float bb = sbias[c];
#pragma unroll
    for (int j = 0; j < 4; ++j) {
      const int r = wv * 16 + hi * 4 + j;
      sm.L[r * 112 + c] = acc[fn][j] + bb;
    }
  }
  __syncthreads();
  // 9 softmaxes per row (576 tasks)
  for (int t = tid; t < 576; t += 256) {
    const int g = t % 9, r = t / 9;
    const int off = (g < 3) ? (g << 4) : (40 + (g << 3));
    const int n = (g == 2) ? 24 : ((g < 2) ? 16 : 8);
    float* pl = &sm.L[r * 112 + off];
    float m = pl[0];
    for (int i2 = 1; i2 < n; ++i2) m = fmaxf(m, pl[i2]);
    float ssum = 0.f;
    for (int i2 = 0; i2 < n; ++i2) { const float ev = __expf(pl[i2] - m); pl[i2] = ev; ssum += ev; }
    const float inv = 1.f / ssum;
    for (int i2 = 0; i2 < n; ++i2) pl[i2] *= inv;
  }
  __syncthreads();
  // combine -> A[r][64]
  {
    const int ee = tid & 7, v = (tid >> 3) & 7, rb = tid >> 6;
    int m0 = 0, m1 = 0, m2 = 0; float s0 = 0.f, s1 = 0.f, s2 = 0.f;
    switch (v) {
      case 0: m0 = ee;      s0 = 1.f;   m1 = 96 + ee;  s1 = ALPHA; break;
      case 1: m0 = 8 + ee;  s0 = 1.f;   break;
      case 2: m0 = 80 + ee; s0 = ALPHA; m1 = 64 + ee;  s1 = ALPHA; break;
      case 3: m0 = 16 + ee; s0 = 1.f;   m1 = 72 + ee;  s1 = BETA;  break;
      case 4: m0 = 24 + ee; s0 = 1.f;   m1 = 88 + ee;  s1 = BETA;  m2 = 104 + ee; s2 = BETA; break;
      case 5: m0 = 32 + ee; s0 = 1.f;   break;
      case 6: m0 = 40 + ee; s0 = 1.f;   break;
      case 7: m0 = 48 + ee; s0 = 1.f;   break;
    }
#pragma unroll
    for (int t = 0; t < 16; ++t) {
      const int r = rb + t * 4;
      const float val = s0 * sm.L[r * 112 + m0] + s1 * sm.L[r * 112 + m1] + s2 * sm.L[r * 112 + m2];
      A[(size_t)(R0 + r) * 64 + (tid & 63)] = val;
    }
  }
}

// ---------------------------------------------------------------------------
// Kernel 3: fused expert GEMM (bf16 MFMA, swizzled LDS) + bias + relu +
// in-register permuted mix (no S round-trip through LDS).
// Block = (e, mt), XCD-chunked: xcd = p&7 owns mt range [xcd*32, xcd*32+32),
// e cycles fastest so the 8 expert-siblings of an X tile share the XCD's L2.
// Output rows b' = e*4096 + mt*16 + o;  o = wr*8 + fm*2 + (hi>>1);
// ep = (hi&1)*4 + j;  pair-reduce over lane^16 sums the two ep halves.
// ---------------------------------------------------------------------------
__global__ __launch_bounds__(256) void k_moe(
    const float* __restrict__ xsh, const float* __restrict__ xt1, const float* __restrict__ xt2,
    const unsigned short* __restrict__ Wbf,
    const float* __restrict__ bsh, const float* __restrict__ bt1, const float* __restrict__ bt2,
    const float* __restrict__ A, float* __restrict__ out) {
  __shared__ struct { unsigned short xs[128 * 64]; unsigned short wsb[128 * 64]; } sm;

  const int tid = threadIdx.x;
  const int lane = tid & 63, wid = tid >> 6;
  const int wr = wid >> 1, wc = wid & 1;
  const int lo = lane & 15, hi = lane >> 4;
  const int p = blockIdx.x;
  const int e = (p >> 3) & 7;
  const int mt = ((p & 7) << 5) | (p >> 6);
  const int R0 = mt * 128;
  const int b0 = e * 4096 + mt * 16;

  const float* xp[3] = { xsh, xt1, xt2 };
  const float* bp[3] = { bsh, bt1, bt2 };
  const int a0i[3] = { 6, 5, 7 };   // out_sh coef vec per set
  const int a1i[3] = { 0, 1, 2 };   // out1 coef vec per set
  const int a2i[3] = { 3, 0, 4 };   // out2 coef vec per set (s==1 masked)

  float part[3][4][4];
#pragma unroll
  for (int k = 0; k < 3; ++k)
#pragma unroll
    for (int fm = 0; fm < 4; ++fm)
#pragma unroll
      for (int fn = 0; fn < 4; ++fn) part[k][fm][fn] = 0.f;

#pragma unroll
  for (int s = 0; s < 3; ++s) {
    const float* __restrict__ X = xp[s];
    const unsigned short* __restrict__ W = Wbf + (size_t)(s * 8 + e) * (128 * 384);
    f32x4 acc[4][4];
#pragma unroll
    for (int i = 0; i < 4; ++i)
#pragma unroll
      for (int j = 0; j < 4; ++j) acc[i][j] = 0.f;

    for (int kc = 0; kc < 6; ++kc) {
      // stage X tile [128 x 64] f32 -> bf16, swizzled
#pragma unroll
      for (int j = 0; j < 8; ++j) {
        const int un = tid + j * 256;                 // 0..2047 quads
        const int row = un >> 4, c4 = (un & 15) << 2;
        const f32x4 v = *(const f32x4*)(X + (size_t)(R0 + row) * 384 + kc * 64 + c4);
        u16x4 pk;
        pk.x = f2bf(v.x); pk.y = f2bf(v.y); pk.z = f2bf(v.z); pk.w = f2bf(v.w);
        *(u16x4*)((char*)sm.xs + row * 128 + SWZB(row, (un & 15) << 3)) = pk;
      }
      // stage W tile [128 x 64] bf16, swizzled
#pragma unroll
      for (int j = 0; j < 4; ++j) {
        const int un = tid + j * 256;                 // 0..1023 16B chunks
        const int row = un >> 3, g = un & 7;
        const u32x4 v = *(const u32x4*)(W + (size_t)row * 384 + kc * 64 + (g << 3));
        *(u32x4*)((char*)sm.wsb + row * 128 + SWZB(row, g << 4)) = v;
      }
      __syncthreads();
#pragma unroll
      for (int kk = 0; kk < 2; ++kk) {
        s16x8 av[4], bv[4];
#pragma unroll
        for (int f = 0; f < 4; ++f) {
          const int ar = wr * 64 + f * 16 + lo;
          const int br = wc * 64 + f * 16 + lo;
          av[f] = *(const s16x8*)((const char*)sm.xs  + ar * 128 + SWZB(ar, kk * 64 + hi * 16));
          bv[f] = *(const s16x8*)((const char*)sm.wsb + br * 128 + SWZB(br, kk * 64 + hi * 16));
        }
#pragma unroll
        for (int fm = 0; fm < 4; ++fm)
#pragma unroll
          for (int fn = 0; fn < 4; ++fn)
            acc[fm][fn] = __builtin_amdgcn_mfma_f32_16x16x32_bf16(av[fm], bv[fn], acc[fm][fn], 0, 0, 0);
      }
      __syncthreads();
    }
    // ---- in-register epilogue: bias + relu + mix-accumulate ----
    float biasv[4];
#pragma unroll
    for (int fn = 0; fn < 4; ++fn) biasv[fn] = bp[s][e * 128 + wc * 64 + fn * 16 + lo];
    const float* Ab = A + (size_t)(b0 + wr * 8 + (hi >> 1)) * 64 + (hi & 1) * 4;
    const int v0 = a0i[s], v1 = a1i[s], v2 = a2i[s];
#pragma unroll
    for (int fm = 0; fm < 4; ++fm) {
      const float* Ar = Ab + fm * 2 * 64;
      const f32x4 c0 = *(const f32x4*)(Ar + v0 * 8);
      const f32x4 c1 = *(const f32x4*)(Ar + v1 * 8);
      f32x4 c2 = {};
      if (s != 1) c2 = *(const f32x4*)(Ar + v2 * 8);
#pragma unroll
      for (int fn = 0; fn < 4; ++fn) {
#pragma unroll
        for (int j = 0; j < 4; ++j) {
          const float sv = fmaxf(acc[fm][fn][j] + biasv[fn], 0.f);
          part[0][fm][fn] = fmaf(c0[j], sv, part[0][fm][fn]);
          part[1][fm][fn] = fmaf(c1[j], sv, part[1][fm][fn]);
          if (s != 1) part[2][fm][fn] = fmaf(c2[j], sv, part[2][fm][fn]);
        }
      }
    }
  }
  // ---- pair-reduce (lane^16 holds the complementary ep half) and store ----
#pragma unroll
  for (int k = 0; k < 3; ++k)
#pragma unroll
    for (int fm = 0; fm < 4; ++fm)
#pragma unroll
      for (int fn = 0; fn < 4; ++fn)
        part[k][fm][fn] += __shfl_xor(part[k][fm][fn], 16);
  if ((hi & 1) == 0) {
#pragma unroll
    for (int k = 0; k < 3; ++k) {
#pragma unroll
      for (int fm = 0; fm < 4; ++fm) {
        const int o = wr * 8 + fm * 2 + (hi >> 1);
        float* dst = out + (size_t)k * (B_DIM * 128) + (size_t)(b0 + o) * 128 + wc * 64 + lo;
#pragma unroll
        for (int fn = 0; fn < 4; ++fn) dst[fn * 16] = part[k][fm][fn];
      }
    }
  }
}

// ---------------------------------------------------------------------------
extern "C" void kernel_launch(void* const* d_in, const int* in_sizes, int n_in,
                              void* d_out, int out_size, void* d_ws, size_t ws_size,
                              hipStream_t stream) {
  const float* xsh = (const float*)d_in[0];
  const float* xt1 = (const float*)d_in[1];
  const float* xt2 = (const float*)d_in[2];
  const float* ui  = (const float*)d_in[3];
  const float* up  = (const float*)d_in[4];
  const float* ip  = (const float*)d_in[5];
  const float* Wsh = (const float*)d_in[6];   const float* bsh = (const float*)d_in[7];
  const float* Wt1 = (const float*)d_in[8];   const float* bt1 = (const float*)d_in[9];
  const float* Wt2 = (const float*)d_in[10];  const float* bt2 = (const float*)d_in[11];
  const float* Wg_sh  = (const float*)d_in[12];  const float* bg_sh  = (const float*)d_in[13];
  const float* Wg_t1  = (const float*)d_in[14];  const float* bg_t1  = (const float*)d_in[15];
  const float* Wg_t2  = (const float*)d_in[16];  const float* bg_t2  = (const float*)d_in[17];
  const float* Wg_sh2 = (const float*)d_in[18];  const float* bg_sh2 = (const float*)d_in[19];
  const float* Wg_t2ip = (const float*)d_in[20]; const float* bg_t2ip = (const float*)d_in[21];
  const float* Wg_t2up = (const float*)d_in[22]; const float* bg_t2up = (const float*)d_in[23];
  const float* Wg_s1ip = (const float*)d_in[24]; const float* bg_s1ip = (const float*)d_in[25];
  const float* Wg_s1up = (const float*)d_in[26]; const float* bg_s1up = (const float*)d_in[27];
  const float* Wg_t1ui = (const float*)d_in[28]; const float* bg_t1ui = (const float*)d_in[29];

  unsigned short* Wbf = (unsigned short*)d_ws;              // 2,359,296 B
  float* A = (float*)((char*)d_ws + 2359296);               // 8,388,608 B (total = round-1 proven footprint)
  float* out = (float*)d_out;

  hipLaunchKernelGGL(k_wconv, dim3(1152), dim3(256), 0, stream, Wsh, Wt1, Wt2, Wbf);
  hipLaunchKernelGGL(k_glog, dim3(512), dim3(256), 0, stream,
                     xsh, xt1, xt2, ui, up, ip,
                     Wg_sh, bg_sh, Wg_t1, bg_t1, Wg_t2, bg_t2, Wg_sh2, bg_sh2,
                     Wg_t2ip, bg_t2ip, Wg_t2up, bg_t2up, Wg_s1ip, bg_s1ip,
                     Wg_s1up, bg_s1up, Wg_t1ui, bg_t1ui, A);
  hipLaunchKernelGGL(k_moe, dim3(2048), dim3(256), 0, stream,
                     xsh, xt1, xt2, Wbf, bsh, bt1, bt2, A, out);
}